// Round 11
// baseline (155.583 us; speedup 1.0000x reference)
//
#include <hip/hip_runtime.h>
#include <hip/hip_fp16.h>
#include <stdint.h>

#define N_NODES 40000
#define D_FEAT 64
#define DEG 32
#define E_EDGES (N_NODES * DEG)
#define G_GRAPHS 200
#define NPG 200          // nodes per graph
#define ATT_SZ 64
#define HID 128
#define NCLS 6

__device__ __forceinline__ float selu_f(float x) {
    const float scale = 1.0507009873554805f;
    const float alpha = 1.6732632423543772f;
    return scale * (x > 0.f ? x : alpha * (__expf(x) - 1.f));
}

// R20 = R19 restructure (matmul commutes with linear aggregation:
//   sum_e V[r]*(x[r]@W^T) = (sum_e V[r]*x[r]) @ W^T, k_node deleted)
// with ONE fix: xb packs x as FP16 (11 mantissa bits), not bf16 (8 bits).
// R19's absmax was 0.03125 (>0.02): pre-GEMM bf16 quantization amplifies
// through the 64-wide W-dot ~3.5x vs the old post-GEMM quantization. fp16
// cuts quantization error 8x -> expected absmax ~0.005. x~N(0,1) fits fp16
// range. Same 2B/elem, same 128B rows, same gather byte volume.

__global__ __launch_bounds__(128) void k_w(const float* __restrict__ Watt,
                                           const float* __restrict__ avec,
                                           float* __restrict__ wbuf) {
    int t = threadIdx.x;
    float s = 0.f;
#pragma unroll
    for (int k = 0; k < ATT_SZ; ++k) s += avec[k] * Watt[k * 128 + t];
    wbuf[t] = s;
}

// P[n]=exp(w1.x[n]), Q[n]=exp(w2.x[n]), xb[n] = fp16(x[n]) packed 128B rows.
// Wave: 8 nodes, lane -> (node=lane>>3, part=lane&7 -> features part*8..+8).
// Blocks 0..49 zero the 200x64 pool (harness poisons ws with 0xAA).
__global__ __launch_bounds__(256) void k_prep(const float* __restrict__ x,
                                              const float* __restrict__ wbuf,
                                              float* __restrict__ P,
                                              float* __restrict__ Q,
                                              uint32_t* __restrict__ xb,
                                              float* __restrict__ pool) {
    __shared__ float w_s[128];
    int tid = threadIdx.x;
    if (blockIdx.x < 50) pool[blockIdx.x * 256 + tid] = 0.f;
    if (tid < 128) w_s[tid] = wbuf[tid];
    __syncthreads();

    int wv = tid >> 6, lane = tid & 63;
    int nl = lane >> 3, part = lane & 7;
    int n = blockIdx.x * 32 + wv * 8 + nl;
    const float4* xr = (const float4*)(x + (size_t)n * 64);
    float4 f0 = xr[part * 2], f1 = xr[part * 2 + 1];

    int k0 = part * 8;
    float s1 = f0.x * w_s[k0];
    s1 += f0.y * w_s[k0 + 1]; s1 += f0.z * w_s[k0 + 2]; s1 += f0.w * w_s[k0 + 3];
    s1 += f1.x * w_s[k0 + 4]; s1 += f1.y * w_s[k0 + 5];
    s1 += f1.z * w_s[k0 + 6]; s1 += f1.w * w_s[k0 + 7];
    float s2 = f0.x * w_s[64 + k0];
    s2 += f0.y * w_s[64 + k0 + 1]; s2 += f0.z * w_s[64 + k0 + 2]; s2 += f0.w * w_s[64 + k0 + 3];
    s2 += f1.x * w_s[64 + k0 + 4]; s2 += f1.y * w_s[64 + k0 + 5];
    s2 += f1.z * w_s[64 + k0 + 6]; s2 += f1.w * w_s[64 + k0 + 7];
    s1 += __shfl_xor(s1, 1, 64); s1 += __shfl_xor(s1, 2, 64); s1 += __shfl_xor(s1, 4, 64);
    s2 += __shfl_xor(s2, 1, 64); s2 += __shfl_xor(s2, 2, 64); s2 += __shfl_xor(s2, 4, 64);
    if (part == 0) { P[n] = __expf(s1); Q[n] = __expf(s2); }

    __half2 h0 = __float22half2_rn(make_float2(f0.x, f0.y));
    __half2 h1 = __float22half2_rn(make_float2(f0.z, f0.w));
    __half2 h2 = __float22half2_rn(make_float2(f1.x, f1.y));
    __half2 h3 = __float22half2_rn(make_float2(f1.z, f1.w));
    ((uint4*)xb)[(size_t)n * 8 + part] =
        make_uint4(__builtin_bit_cast(uint32_t, h0), __builtin_bit_cast(uint32_t, h1),
                   __builtin_bit_cast(uint32_t, h2), __builtin_bit_cast(uint32_t, h3));
}

// V[n] = P[n] / (Q[n] * sum_{e in [32n,32n+32)} P[row[e]])
__global__ __launch_bounds__(256) void k_edges(const int* __restrict__ row,
                                               const float* __restrict__ P,
                                               const float* __restrict__ Q,
                                               float* __restrict__ V) {
    int e = blockIdx.x * 256 + threadIdx.x;
    float p = P[row[e]];
#pragma unroll
    for (int off = 16; off; off >>= 1)
        p += __shfl_xor(p, off, 32);
    if ((threadIdx.x & 31) == 0) {
        int n = e >> 5;
        V[n] = P[n] / (Q[n] * p);
    }
}

// agg[n][:] = sum_j V[r_j] * xb[r_j][:]  (raw rows out; GEMM/selu/pool -> k_mm).
// Gather structure identical to the proven ~25us version: block = 32 nodes,
// 1024 edge records in LDS, wave: 8 nodes, quarter q gathers row s*4+q as uint2.
__global__ __launch_bounds__(256) void k_agg(const int* __restrict__ row,
                                             const float* __restrict__ V,
                                             const uint32_t* __restrict__ xb,
                                             float* __restrict__ agg) {
    __shared__ float2 meta[1024];        // (V[r], bitcast(r*128))
    int tid = threadIdx.x;
    int n0 = blockIdx.x * 32;

    int4 r4 = ((const int4*)(row + (size_t)n0 * 32))[tid];
    meta[4 * tid + 0] = make_float2(V[r4.x], __builtin_bit_cast(float, r4.x << 7));
    meta[4 * tid + 1] = make_float2(V[r4.y], __builtin_bit_cast(float, r4.y << 7));
    meta[4 * tid + 2] = make_float2(V[r4.z], __builtin_bit_cast(float, r4.z << 7));
    meta[4 * tid + 3] = make_float2(V[r4.w], __builtin_bit_cast(float, r4.w << 7));
    __syncthreads();

    int wv = tid >> 6, lane = tid & 63;
    int q = lane >> 4, fi = lane & 15;
    int nw0 = n0 + wv * 8;
    const char* xbc = (const char*)xb;
#pragma unroll 1
    for (int nn = 0; nn < 8; ++nn) {
        int n = nw0 + nn;
        int base = (wv * 8 + nn) * 32;
        float4 a = make_float4(0.f, 0.f, 0.f, 0.f);
#pragma unroll
        for (int s = 0; s < 8; ++s) {
            float2 m = meta[base + s * 4 + q];
            uint32_t rbyte = __builtin_bit_cast(uint32_t, m.y);
            uint2 u = *(const uint2*)(xbc + rbyte + fi * 8);
            float2 g0 = __half22float2(__builtin_bit_cast(__half2, u.x));
            float2 g1 = __half22float2(__builtin_bit_cast(__half2, u.y));
            a.x += m.x * g0.x;
            a.y += m.x * g0.y;
            a.z += m.x * g1.x;
            a.w += m.x * g1.y;
        }
        a.x += __shfl_xor(a.x, 16, 64); a.x += __shfl_xor(a.x, 32, 64);
        a.y += __shfl_xor(a.y, 16, 64); a.y += __shfl_xor(a.y, 32, 64);
        a.z += __shfl_xor(a.z, 16, 64); a.z += __shfl_xor(a.z, 32, 64);
        a.w += __shfl_xor(a.w, 16, 64); a.w += __shfl_xor(a.w, 32, 64);
        if (q == 0) *(float4*)&agg[(size_t)n * 64 + 4 * fi] = a;
    }
}

// h[n] = selu(Q[n]/32 * (agg[n] @ Wlin^T) + blin); pool[g] += h[n].
// Wave: 8 nodes (one graph), lane -> (node=lane>>3, dg=lane&7 -> outs dg*8..+8).
// W_s padded to 65: rows 8 apart land on distinct banks for scalar reads.
__global__ __launch_bounds__(256) void k_mm(const float* __restrict__ agg,
                                            const float* __restrict__ Wlin,
                                            const float* __restrict__ Q,
                                            const float* __restrict__ blin,
                                            float* __restrict__ pool) {
    __shared__ float W_s[64 * 65];
    int tid = threadIdx.x;
#pragma unroll
    for (int s = 0; s < 16; ++s) {
        int idx = tid + s * 256;
        W_s[(idx >> 6) * 65 + (idx & 63)] = Wlin[idx];
    }
    __syncthreads();

    int wv = tid >> 6, lane = tid & 63;
    int nl = lane >> 3, dg = lane & 7;
    int n = blockIdx.x * 32 + wv * 8 + nl;
    const float4* ar = (const float4*)(agg + (size_t)n * 64);
    float4 av[16];
#pragma unroll
    for (int i = 0; i < 16; ++i) av[i] = ar[i];
    float qn = Q[n] * (1.f / 32.f);

    float hv[8];
#pragma unroll
    for (int j = 0; j < 8; ++j) {
        const float* wr = &W_s[(dg * 8 + j) * 65];
        float s = 0.f;
#pragma unroll
        for (int i = 0; i < 16; ++i) {
            float4 a4 = av[i];
            s += a4.x * wr[4 * i];     s += a4.y * wr[4 * i + 1];
            s += a4.z * wr[4 * i + 2]; s += a4.w * wr[4 * i + 3];
        }
        hv[j] = selu_f(qn * s + blin[dg * 8 + j]);
    }
#pragma unroll
    for (int j = 0; j < 8; ++j) {        // pool over the wave's 8 nodes
        hv[j] += __shfl_xor(hv[j], 8, 64);
        hv[j] += __shfl_xor(hv[j], 16, 64);
        hv[j] += __shfl_xor(hv[j], 32, 64);
    }
    if (nl == 0) {
        int g = (blockIdx.x * 32 + wv * 8) / NPG;
        float* pp = &pool[g * 64 + dg * 8];
#pragma unroll
        for (int j = 0; j < 8; ++j) atomicAdd(pp + j, hv[j]);
    }
}

// pooled = pool/200; hcls = selu(W1 @ pooled + b1); logits = W2 @ hcls + b2; softmax
__global__ __launch_bounds__(128) void k_cls(const float* __restrict__ pool,
                                             const float* __restrict__ W1,
                                             const float* __restrict__ b1,
                                             const float* __restrict__ W2,
                                             const float* __restrict__ b2,
                                             float* __restrict__ out) {
    __shared__ float ps[64];
    __shared__ float hc[HID];
    __shared__ float lg[NCLS];
    int t = threadIdx.x, g = blockIdx.x;
    if (t < 64) ps[t] = pool[g * 64 + t] * (1.f / NPG);
    __syncthreads();
    float s = b1[t];
    const float4* w14 = (const float4*)(W1 + t * 64);
    const float4* ps4 = (const float4*)ps;
#pragma unroll
    for (int kk = 0; kk < 16; ++kk) {
        float4 w = w14[kk], p = ps4[kk];
        s += w.x * p.x; s += w.y * p.y; s += w.z * p.z; s += w.w * p.w;
    }
    hc[t] = selu_f(s);
    __syncthreads();
    if (t < NCLS) {
        float l = b2[t];
        const float4* w24 = (const float4*)(W2 + t * 128);
        const float4* hc4 = (const float4*)hc;
        for (int kk = 0; kk < 32; ++kk) {
            float4 w = w24[kk], h = hc4[kk];
            l += w.x * h.x; l += w.y * h.y; l += w.z * h.z; l += w.w * h.w;
        }
        lg[t] = l;
    }
    __syncthreads();
    if (t == 0) {
        float m = lg[0];
        for (int c = 1; c < NCLS; ++c) m = fmaxf(m, lg[c]);
        float ex[NCLS], sum = 0.f;
        for (int c = 0; c < NCLS; ++c) { ex[c] = __expf(lg[c] - m); sum += ex[c]; }
        for (int c = 0; c < NCLS; ++c) out[g * NCLS + c] = ex[c] / sum;
    }
}

extern "C" void kernel_launch(void* const* d_in, const int* in_sizes, int n_in,
                              void* d_out, int out_size, void* d_ws, size_t ws_size,
                              hipStream_t stream) {
    const float* x    = (const float*)d_in[0];
    const float* Wlin = (const float*)d_in[1];
    const float* blin = (const float*)d_in[2];
    const float* Watt = (const float*)d_in[3];
    const float* avec = (const float*)d_in[4];
    const float* W1   = (const float*)d_in[5];
    const float* b1   = (const float*)d_in[6];
    const float* W2   = (const float*)d_in[7];
    const float* b2   = (const float*)d_in[8];
    const int*   row  = (const int*)d_in[9];   // edge_index[0]; edge_index[1] is structured
    float* out = (float*)d_out;

    // ws: P[N] | Q[N] | V[N] | pool[200*64] | wbuf[128] | xb[N*32 u32] | agg[N*64 f32]
    float* P    = (float*)d_ws;
    float* Q    = P + N_NODES;
    float* V    = Q + N_NODES;
    float* pool = V + N_NODES;
    float* wbuf = pool + G_GRAPHS * 64;
    uint32_t* xb = (uint32_t*)(wbuf + 128);
    float* agg  = (float*)(xb + (size_t)N_NODES * 32);

    k_w<<<1, 128, 0, stream>>>(Watt, avec, wbuf);
    k_prep<<<N_NODES / 32, 256, 0, stream>>>(x, wbuf, P, Q, xb, pool);
    k_edges<<<E_EDGES / 256, 256, 0, stream>>>(row, P, Q, V);
    k_agg<<<N_NODES / 32, 256, 0, stream>>>(row, V, xb, agg);
    k_mm<<<N_NODES / 32, 256, 0, stream>>>(agg, Wlin, Q, blin, pool);
    k_cls<<<G_GRAPHS, 128, 0, stream>>>(pool, W1, b1, W2, b2, out);
}

// Round 12
// 139.944 us; speedup vs baseline: 1.1118x; 1.1118x over previous
//
#include <hip/hip_runtime.h>
#include <hip/hip_bf16.h>
#include <stdint.h>

#define N_NODES 40000
#define D_FEAT 64
#define DEG 32
#define E_EDGES (N_NODES * DEG)
#define G_GRAPHS 200
#define NPG 200          // nodes per graph
#define ATT_SZ 64
#define HID 128
#define NCLS 6
#define XS 69            // padded LDS row stride: b128 reads <=2-way banked

__device__ __forceinline__ float selu_f(float x) {
    const float scale = 1.0507009873554805f;
    const float alpha = 1.6732632423543772f;
    return scale * (x > 0.f ? x : alpha * (__expf(x) - 1.f));
}

__device__ __forceinline__ uint32_t f2bf(float f) {   // fp32 -> bf16 bits (RNE)
    uint32_t u = __builtin_bit_cast(uint32_t, f);
    return (u + 0x7fffu + ((u >> 16) & 1u)) >> 16;
}
__device__ __forceinline__ float bflo(uint32_t u) { return __builtin_bit_cast(float, u << 16); }
__device__ __forceinline__ float bfhi(uint32_t u) { return __builtin_bit_cast(float, u & 0xffff0000u); }

// R21 = R15 base (129.1us best) + XCD-local k_agg gather ONLY.
// Session ledger: R20 (k_node deleted, GEMM moved post-gather) was +26us —
// proof the ~43us "k_node mystery" is REGIME-level: any kernel streaming
// cold post-poison memory runs ~10x below roofline, independent of structure.
// So: minimum cold passes (R15's 4-kernel chain) + attack the one pipe-level
// inefficiency left: k_agg's gather runs at 6.6TB/s = L3/remote-XCD BW because
// yb (5.1MB) stripes across 8 XCD L2s (7/8 of gathers remote). Fix isolated to
// k_agg (k_node UNTOUCHED, R11's confound removed): 128B yb rows kept; block
// b&1 selects the 64B half-line (features 32h..32h+31) of every row. With
// round-robin blockIdx->XCD, even blocks touch only even 64B lines (2.56MB)
// -> per-XCD working set < 4MB L2 -> local-L2 gather (~34TB/s).
__global__ __launch_bounds__(256) void k_node(const float* __restrict__ x,
                                              const float* __restrict__ Wlin,
                                              const float* __restrict__ Watt,
                                              const float* __restrict__ avec,
                                              float* __restrict__ P,
                                              float* __restrict__ Q,
                                              uint32_t* __restrict__ yb,
                                              float* __restrict__ pool) {
    __shared__ float xs[160 * XS];
    __shared__ float ws[64 * XS];
    __shared__ float ws_w[128];
    int tid = threadIdx.x;
    int n0 = blockIdx.x * 160;
    if (blockIdx.x < 50) pool[blockIdx.x * 256 + tid] = 0.f;

    const float4* x4 = (const float4*)(x + (size_t)n0 * 64);
    const float4* W4 = (const float4*)Wlin;
#pragma unroll
    for (int s = 0; s < 10; ++s) {        // 2560 float4 = 160 rows x 16
        int idx = tid + s * 256, r = idx >> 4, kk = idx & 15;
        *(float4*)&xs[r * XS + kk * 4] = x4[idx];
    }
#pragma unroll
    for (int s = 0; s < 4; ++s) {         // 1024 float4 = 64 rows x 16
        int idx = tid + s * 256, r = idx >> 4, kk = idx & 15;
        *(float4*)&ws[r * XS + kk * 4] = W4[idx];
    }
    if (tid < 128) {                      // w[j] = sum_k avec[k]*Watt[k][j]
        float s = 0.f;
        for (int k = 0; k < ATT_SZ; ++k) s += avec[k] * Watt[k * 128 + tid];
        ws_w[tid] = s;
    }
    __syncthreads();

    if (tid < 160) {                      // P/Q: 1 lane per node, 64 k each
        float s1 = 0.f, s2 = 0.f;
#pragma unroll 8
        for (int k = 0; k < 64; ++k) {
            float xv = xs[tid * XS + k];
            s1 += xv * ws_w[k];
            s2 += xv * ws_w[64 + k];
        }
        P[n0 + tid] = __expf(s1);
        Q[n0 + tid] = __expf(s2);
    }

    int tm = tid >> 4, tf = tid & 15;     // rows tm+16i (i<10), cols 4tf..4tf+3
    float acc[10][4];
#pragma unroll
    for (int i = 0; i < 10; ++i)
#pragma unroll
        for (int j = 0; j < 4; ++j) acc[i][j] = 0.f;
#pragma unroll 2                          // R15: keep body ~3KB -> I$-resident loop
    for (int kk = 0; kk < 16; ++kk) {
        float4 wv[4];
#pragma unroll
        for (int j = 0; j < 4; ++j) wv[j] = *(const float4*)&ws[(4 * tf + j) * XS + kk * 4];
#pragma unroll
        for (int i = 0; i < 10; ++i) {
            float4 xv = *(const float4*)&xs[(tm + 16 * i) * XS + kk * 4];
#pragma unroll
            for (int j = 0; j < 4; ++j)
                acc[i][j] += xv.x * wv[j].x + xv.y * wv[j].y
                           + xv.z * wv[j].z + xv.w * wv[j].w;
        }
    }
#pragma unroll
    for (int i = 0; i < 10; ++i) {
        int m = n0 + tm + 16 * i;
        uint32_t p0 = f2bf(acc[i][0]) | (f2bf(acc[i][1]) << 16);
        uint32_t p1 = f2bf(acc[i][2]) | (f2bf(acc[i][3]) << 16);
        *(uint2*)&yb[(size_t)m * 32 + tf * 2] = make_uint2(p0, p1);
    }
}

// V[n] = P[n] / (Q[n] * sum_{e in [32n,32n+32)} P[row[e]])
__global__ __launch_bounds__(256) void k_edges(const int* __restrict__ row,
                                               const float* __restrict__ P,
                                               const float* __restrict__ Q,
                                               float* __restrict__ V) {
    int e = blockIdx.x * 256 + threadIdx.x;
    float p = P[row[e]];
#pragma unroll
    for (int off = 16; off; off >>= 1)
        p += __shfl_xor(p, off, 32);
    if ((threadIdx.x & 31) == 0) {
        int n = e >> 5;
        V[n] = P[n] / (Q[n] * p);
    }
}

// h[n][32h..32h+31] for half h = b&1: selu(Q[n]/32 * sum_j V[r_j]*y[r_j][..] + blin[..]),
// pooled by graph. Block = 32 nodes x one 64B half-line of each 128B yb row.
// Wave: 8 nodes; row-slot sr (8 lanes x 8B) gathers rows s*8+sr, s=0..3.
// Even/odd blocks touch disjoint 2.56MB line sets -> XCD-local L2 after warmup.
__global__ __launch_bounds__(256) void k_agg(const int* __restrict__ row,
                                             const float* __restrict__ V,
                                             const float* __restrict__ Q,
                                             const uint32_t* __restrict__ yb,
                                             const float* __restrict__ blin,
                                             float* __restrict__ pool) {
    __shared__ float2 meta[1024];        // (V[r], bitcast(r*128))
    int tid = threadIdx.x;
    int nb = blockIdx.x >> 1;            // node block 0..1249
    int half = blockIdx.x & 1;           // feature half: XCD-parity-bound
    int n0 = nb * 32;

    int4 r4 = ((const int4*)(row + (size_t)n0 * 32))[tid];
    meta[4 * tid + 0] = make_float2(V[r4.x], __builtin_bit_cast(float, r4.x << 7));
    meta[4 * tid + 1] = make_float2(V[r4.y], __builtin_bit_cast(float, r4.y << 7));
    meta[4 * tid + 2] = make_float2(V[r4.z], __builtin_bit_cast(float, r4.z << 7));
    meta[4 * tid + 3] = make_float2(V[r4.w], __builtin_bit_cast(float, r4.w << 7));
    __syncthreads();

    int wv = tid >> 6, lane = tid & 63;
    int sr = lane >> 3, fi = lane & 7;   // sr: row-slot (8 rows/instr), fi: 8B chunk
    float4 bl4 = ((const float4*)blin)[half * 8 + fi];
    int nw0 = n0 + wv * 8;               // 8 aligned nodes: one graph (8 | 200)
    float4 pacc = make_float4(0.f, 0.f, 0.f, 0.f);
    const char* ybc = (const char*)yb + half * 64;   // 64B half-line of each row
#pragma unroll 1
    for (int nn = 0; nn < 8; ++nn) {
        int n = nw0 + nn;
        int base = (wv * 8 + nn) * 32;
        float4 a = make_float4(0.f, 0.f, 0.f, 0.f);
#pragma unroll
        for (int s = 0; s < 4; ++s) {
            float2 m = meta[base + s * 8 + sr];
            uint32_t rbyte = __builtin_bit_cast(uint32_t, m.y);
            uint2 u = *(const uint2*)(ybc + rbyte + fi * 8);
            a.x += m.x * bflo(u.x);
            a.y += m.x * bfhi(u.x);
            a.z += m.x * bflo(u.y);
            a.w += m.x * bfhi(u.y);
        }
        a.x += __shfl_xor(a.x, 8, 64); a.x += __shfl_xor(a.x, 16, 64); a.x += __shfl_xor(a.x, 32, 64);
        a.y += __shfl_xor(a.y, 8, 64); a.y += __shfl_xor(a.y, 16, 64); a.y += __shfl_xor(a.y, 32, 64);
        a.z += __shfl_xor(a.z, 8, 64); a.z += __shfl_xor(a.z, 16, 64); a.z += __shfl_xor(a.z, 32, 64);
        a.w += __shfl_xor(a.w, 8, 64); a.w += __shfl_xor(a.w, 16, 64); a.w += __shfl_xor(a.w, 32, 64);
        float qn = Q[n] * (1.f / 32.f);
        pacc.x += selu_f(qn * a.x + bl4.x);
        pacc.y += selu_f(qn * a.y + bl4.y);
        pacc.z += selu_f(qn * a.z + bl4.z);
        pacc.w += selu_f(qn * a.w + bl4.w);
    }
    if (sr == 0) {
        int g = nw0 / NPG;
        float* pp = &pool[g * 64 + half * 32 + 4 * fi];
        atomicAdd(pp + 0, pacc.x);
        atomicAdd(pp + 1, pacc.y);
        atomicAdd(pp + 2, pacc.z);
        atomicAdd(pp + 3, pacc.w);
    }
}

// pooled = pool/200; hcls = selu(W1 @ pooled + b1); logits = W2 @ hcls + b2; softmax
__global__ __launch_bounds__(128) void k_cls(const float* __restrict__ pool,
                                             const float* __restrict__ W1,
                                             const float* __restrict__ b1,
                                             const float* __restrict__ W2,
                                             const float* __restrict__ b2,
                                             float* __restrict__ out) {
    __shared__ float ps[64];
    __shared__ float hc[HID];
    __shared__ float lg[NCLS];
    int t = threadIdx.x, g = blockIdx.x;
    if (t < 64) ps[t] = pool[g * 64 + t] * (1.f / NPG);
    __syncthreads();
    float s = b1[t];
    const float4* w14 = (const float4*)(W1 + t * 64);
    const float4* ps4 = (const float4*)ps;
#pragma unroll
    for (int kk = 0; kk < 16; ++kk) {
        float4 w = w14[kk], p = ps4[kk];
        s += w.x * p.x; s += w.y * p.y; s += w.z * p.z; s += w.w * p.w;
    }
    hc[t] = selu_f(s);
    __syncthreads();
    if (t < NCLS) {
        float l = b2[t];
        const float4* w24 = (const float4*)(W2 + t * 128);
        const float4* hc4 = (const float4*)hc;
        for (int kk = 0; kk < 32; ++kk) {
            float4 w = w24[kk], h = hc4[kk];
            l += w.x * h.x; l += w.y * h.y; l += w.z * h.z; l += w.w * h.w;
        }
        lg[t] = l;
    }
    __syncthreads();
    if (t == 0) {
        float m = lg[0];
        for (int c = 1; c < NCLS; ++c) m = fmaxf(m, lg[c]);
        float ex[NCLS], sum = 0.f;
        for (int c = 0; c < NCLS; ++c) { ex[c] = __expf(lg[c] - m); sum += ex[c]; }
        for (int c = 0; c < NCLS; ++c) out[g * NCLS + c] = ex[c] / sum;
    }
}

extern "C" void kernel_launch(void* const* d_in, const int* in_sizes, int n_in,
                              void* d_out, int out_size, void* d_ws, size_t ws_size,
                              hipStream_t stream) {
    const float* x    = (const float*)d_in[0];
    const float* Wlin = (const float*)d_in[1];
    const float* blin = (const float*)d_in[2];
    const float* Watt = (const float*)d_in[3];
    const float* avec = (const float*)d_in[4];
    const float* W1   = (const float*)d_in[5];
    const float* b1   = (const float*)d_in[6];
    const float* W2   = (const float*)d_in[7];
    const float* b2   = (const float*)d_in[8];
    const int*   row  = (const int*)d_in[9];   // edge_index[0]; edge_index[1] is structured
    float* out = (float*)d_out;

    // ws layout: P[N] | Q[N] | V[N] | pool[200*64] | yb[N*32 u32 (bf16x2 y, 128B rows)]
    float* P    = (float*)d_ws;
    float* Q    = P + N_NODES;
    float* V    = Q + N_NODES;
    float* pool = V + N_NODES;
    uint32_t* yb = (uint32_t*)(pool + G_GRAPHS * 64);

    k_node<<<N_NODES / 160, 256, 0, stream>>>(x, Wlin, Watt, avec, P, Q, yb, pool);
    k_edges<<<E_EDGES / 256, 256, 0, stream>>>(row, P, Q, V);
    k_agg<<<(N_NODES / 32) * 2, 256, 0, stream>>>(row, V, Q, yb, blin, pool);
    k_cls<<<G_GRAPHS, 128, 0, stream>>>(pool, W1, b1, W2, b2, out);
}

// Round 13
// 135.030 us; speedup vs baseline: 1.1522x; 1.0364x over previous
//
#include <hip/hip_runtime.h>
#include <hip/hip_bf16.h>
#include <stdint.h>

#define N_NODES 40000
#define D_FEAT 64
#define DEG 32
#define E_EDGES (N_NODES * DEG)
#define G_GRAPHS 200
#define NPG 200          // nodes per graph
#define ATT_SZ 64
#define HID 128
#define NCLS 6
#define XS 69            // padded LDS row stride: b128 reads <=2-way banked

__device__ __forceinline__ float selu_f(float x) {
    const float scale = 1.0507009873554805f;
    const float alpha = 1.6732632423543772f;
    return scale * (x > 0.f ? x : alpha * (__expf(x) - 1.f));
}

__device__ __forceinline__ uint32_t f2bf(float f) {   // fp32 -> bf16 bits (RNE)
    uint32_t u = __builtin_bit_cast(uint32_t, f);
    return (u + 0x7fffu + ((u >> 16) & 1u)) >> 16;
}
__device__ __forceinline__ float bflo(uint32_t u) { return __builtin_bit_cast(float, u << 16); }
__device__ __forceinline__ float bfhi(uint32_t u) { return __builtin_bit_cast(float, u & 0xffff0000u); }

// R22 = R15 base (129.1us best; R21's XCD split regressed, k_agg closed) +
// k_touch PREFETCH. Theory: k_node's ~35-44us unexplained stall is COLD-READ
// starvation — the per-iteration 268MB poison fill evicts L2+L3; k_node then
// streams 10MB of x with only 250 blocks (~300 GB/s effective, vs the fill's
// own 6 TB/s with thousands of blocks). Fix: k_touch (2048 blocks) grid-strides
// x + row at near-roofline (~4us), leaving them L3-warm (15MB << 256MB) for
// k_node/k_edges/k_agg. Also the owed attribution experiment: if null, the
// stall is store/drain-side, not read-side.
__global__ __launch_bounds__(256) void k_touch(const float* __restrict__ x,
                                               const int* __restrict__ row,
                                               float* __restrict__ dummy) {
    float acc = 0.f;
    int t = blockIdx.x * 256 + threadIdx.x;           // 524288 threads
    const float4* x4 = (const float4*)x;
#pragma unroll 2
    for (int i = t; i < (N_NODES * D_FEAT / 4); i += 524288) {   // 640000 float4
        float4 v = x4[i];
        acc += v.x + v.y + v.z + v.w;
    }
    const int4* r4 = (const int4*)row;
    for (int i = t; i < (E_EDGES / 4); i += 524288) {            // 320000 int4
        int4 v = r4[i];
        acc += (float)(v.x ^ v.y ^ v.z ^ v.w);
    }
    if ((int)blockIdx.x < 0) dummy[0] = acc;   // never true: keeps loads live
}

// Fused: w = a_vec @ W_att (per-block recompute), P/Q = exp(w.x), y = x @ Wlin^T
// (bf16-packed). R15 config: 160-node tile, 256 thr, 10x4 microtile, kk unroll 2.
// Blocks 0..49 zero the 200x64 pool (harness poisons ws with 0xAA).
__global__ __launch_bounds__(256) void k_node(const float* __restrict__ x,
                                              const float* __restrict__ Wlin,
                                              const float* __restrict__ Watt,
                                              const float* __restrict__ avec,
                                              float* __restrict__ P,
                                              float* __restrict__ Q,
                                              uint32_t* __restrict__ yb,
                                              float* __restrict__ pool) {
    __shared__ float xs[160 * XS];
    __shared__ float ws[64 * XS];
    __shared__ float ws_w[128];
    int tid = threadIdx.x;
    int n0 = blockIdx.x * 160;
    if (blockIdx.x < 50) pool[blockIdx.x * 256 + tid] = 0.f;

    const float4* x4 = (const float4*)(x + (size_t)n0 * 64);
    const float4* W4 = (const float4*)Wlin;
#pragma unroll
    for (int s = 0; s < 10; ++s) {        // 2560 float4 = 160 rows x 16
        int idx = tid + s * 256, r = idx >> 4, kk = idx & 15;
        *(float4*)&xs[r * XS + kk * 4] = x4[idx];
    }
#pragma unroll
    for (int s = 0; s < 4; ++s) {         // 1024 float4 = 64 rows x 16
        int idx = tid + s * 256, r = idx >> 4, kk = idx & 15;
        *(float4*)&ws[r * XS + kk * 4] = W4[idx];
    }
    if (tid < 128) {                      // w[j] = sum_k avec[k]*Watt[k][j]
        float s = 0.f;
        for (int k = 0; k < ATT_SZ; ++k) s += avec[k] * Watt[k * 128 + tid];
        ws_w[tid] = s;
    }
    __syncthreads();

    if (tid < 160) {                      // P/Q: 1 lane per node, 64 k each
        float s1 = 0.f, s2 = 0.f;
#pragma unroll 8
        for (int k = 0; k < 64; ++k) {
            float xv = xs[tid * XS + k];
            s1 += xv * ws_w[k];
            s2 += xv * ws_w[64 + k];
        }
        P[n0 + tid] = __expf(s1);
        Q[n0 + tid] = __expf(s2);
    }

    int tm = tid >> 4, tf = tid & 15;     // rows tm+16i (i<10), cols 4tf..4tf+3
    float acc[10][4];
#pragma unroll
    for (int i = 0; i < 10; ++i)
#pragma unroll
        for (int j = 0; j < 4; ++j) acc[i][j] = 0.f;
#pragma unroll 2                          // R15: keep body ~3KB -> I$-resident loop
    for (int kk = 0; kk < 16; ++kk) {
        float4 wv[4];
#pragma unroll
        for (int j = 0; j < 4; ++j) wv[j] = *(const float4*)&ws[(4 * tf + j) * XS + kk * 4];
#pragma unroll
        for (int i = 0; i < 10; ++i) {
            float4 xv = *(const float4*)&xs[(tm + 16 * i) * XS + kk * 4];
#pragma unroll
            for (int j = 0; j < 4; ++j)
                acc[i][j] += xv.x * wv[j].x + xv.y * wv[j].y
                           + xv.z * wv[j].z + xv.w * wv[j].w;
        }
    }
#pragma unroll
    for (int i = 0; i < 10; ++i) {
        int m = n0 + tm + 16 * i;
        uint32_t p0 = f2bf(acc[i][0]) | (f2bf(acc[i][1]) << 16);
        uint32_t p1 = f2bf(acc[i][2]) | (f2bf(acc[i][3]) << 16);
        *(uint2*)&yb[(size_t)m * 32 + tf * 2] = make_uint2(p0, p1);
    }
}

// V[n] = P[n] / (Q[n] * sum_{e in [32n,32n+32)} P[row[e]])
__global__ __launch_bounds__(256) void k_edges(const int* __restrict__ row,
                                               const float* __restrict__ P,
                                               const float* __restrict__ Q,
                                               float* __restrict__ V) {
    int e = blockIdx.x * 256 + threadIdx.x;
    float p = P[row[e]];
#pragma unroll
    for (int off = 16; off; off >>= 1)
        p += __shfl_xor(p, off, 32);
    if ((threadIdx.x & 31) == 0) {
        int n = e >> 5;
        V[n] = P[n] / (Q[n] * p);
    }
}

// h[n][:] = selu( Q[n]/32 * sum_j V[r_j]*y[r_j][:] + b_lin ), pooled by graph.
// Block = 32 nodes. 1024 edge records (V[r], r*128) staged in LDS. Wave: 8 nodes;
// quarter q gathers row s*4+q as uint2 (16 lanes x 8B = 128B row; 4 rows/instr).
// Serialized node loop (unroll 1): measured best.
__global__ __launch_bounds__(256) void k_agg(const int* __restrict__ row,
                                             const float* __restrict__ V,
                                             const float* __restrict__ Q,
                                             const uint32_t* __restrict__ yb,
                                             const float* __restrict__ blin,
                                             float* __restrict__ pool) {
    __shared__ float2 meta[1024];        // (V[r], bitcast(r*128))
    int tid = threadIdx.x;
    int n0 = blockIdx.x * 32;

    int4 r4 = ((const int4*)(row + (size_t)n0 * 32))[tid];
    meta[4 * tid + 0] = make_float2(V[r4.x], __builtin_bit_cast(float, r4.x << 7));
    meta[4 * tid + 1] = make_float2(V[r4.y], __builtin_bit_cast(float, r4.y << 7));
    meta[4 * tid + 2] = make_float2(V[r4.z], __builtin_bit_cast(float, r4.z << 7));
    meta[4 * tid + 3] = make_float2(V[r4.w], __builtin_bit_cast(float, r4.w << 7));
    __syncthreads();

    int wv = tid >> 6, lane = tid & 63;
    int q = lane >> 4, fi = lane & 15;
    float4 bl4 = ((const float4*)blin)[fi];
    int nw0 = n0 + wv * 8;               // 8 aligned nodes: one graph (8 | 200)
    float4 pacc = make_float4(0.f, 0.f, 0.f, 0.f);
    const char* ybc = (const char*)yb;
#pragma unroll 1
    for (int nn = 0; nn < 8; ++nn) {
        int n = nw0 + nn;
        int base = (wv * 8 + nn) * 32;
        float4 a = make_float4(0.f, 0.f, 0.f, 0.f);
#pragma unroll
        for (int s = 0; s < 8; ++s) {
            float2 m = meta[base + s * 4 + q];
            uint32_t rbyte = __builtin_bit_cast(uint32_t, m.y);
            uint2 u = *(const uint2*)(ybc + rbyte + fi * 8);
            a.x += m.x * bflo(u.x);
            a.y += m.x * bfhi(u.x);
            a.z += m.x * bflo(u.y);
            a.w += m.x * bfhi(u.y);
        }
        a.x += __shfl_xor(a.x, 16, 64); a.x += __shfl_xor(a.x, 32, 64);
        a.y += __shfl_xor(a.y, 16, 64); a.y += __shfl_xor(a.y, 32, 64);
        a.z += __shfl_xor(a.z, 16, 64); a.z += __shfl_xor(a.z, 32, 64);
        a.w += __shfl_xor(a.w, 16, 64); a.w += __shfl_xor(a.w, 32, 64);
        float qn = Q[n] * (1.f / 32.f);
        pacc.x += selu_f(qn * a.x + bl4.x);
        pacc.y += selu_f(qn * a.y + bl4.y);
        pacc.z += selu_f(qn * a.z + bl4.z);
        pacc.w += selu_f(qn * a.w + bl4.w);
    }
    if (q == 0) {
        int g = nw0 / NPG;
        float* pp = &pool[g * 64 + 4 * fi];
        atomicAdd(pp + 0, pacc.x);
        atomicAdd(pp + 1, pacc.y);
        atomicAdd(pp + 2, pacc.z);
        atomicAdd(pp + 3, pacc.w);
    }
}

// pooled = pool/200; hcls = selu(W1 @ pooled + b1); logits = W2 @ hcls + b2; softmax
__global__ __launch_bounds__(128) void k_cls(const float* __restrict__ pool,
                                             const float* __restrict__ W1,
                                             const float* __restrict__ b1,
                                             const float* __restrict__ W2,
                                             const float* __restrict__ b2,
                                             float* __restrict__ out) {
    __shared__ float ps[64];
    __shared__ float hc[HID];
    __shared__ float lg[NCLS];
    int t = threadIdx.x, g = blockIdx.x;
    if (t < 64) ps[t] = pool[g * 64 + t] * (1.f / NPG);
    __syncthreads();
    float s = b1[t];
    const float4* w14 = (const float4*)(W1 + t * 64);
    const float4* ps4 = (const float4*)ps;
#pragma unroll
    for (int kk = 0; kk < 16; ++kk) {
        float4 w = w14[kk], p = ps4[kk];
        s += w.x * p.x; s += w.y * p.y; s += w.z * p.z; s += w.w * p.w;
    }
    hc[t] = selu_f(s);
    __syncthreads();
    if (t < NCLS) {
        float l = b2[t];
        const float4* w24 = (const float4*)(W2 + t * 128);
        const float4* hc4 = (const float4*)hc;
        for (int kk = 0; kk < 32; ++kk) {
            float4 w = w24[kk], h = hc4[kk];
            l += w.x * h.x; l += w.y * h.y; l += w.z * h.z; l += w.w * h.w;
        }
        lg[t] = l;
    }
    __syncthreads();
    if (t == 0) {
        float m = lg[0];
        for (int c = 1; c < NCLS; ++c) m = fmaxf(m, lg[c]);
        float ex[NCLS], sum = 0.f;
        for (int c = 0; c < NCLS; ++c) { ex[c] = __expf(lg[c] - m); sum += ex[c]; }
        for (int c = 0; c < NCLS; ++c) out[g * NCLS + c] = ex[c] / sum;
    }
}

extern "C" void kernel_launch(void* const* d_in, const int* in_sizes, int n_in,
                              void* d_out, int out_size, void* d_ws, size_t ws_size,
                              hipStream_t stream) {
    const float* x    = (const float*)d_in[0];
    const float* Wlin = (const float*)d_in[1];
    const float* blin = (const float*)d_in[2];
    const float* Watt = (const float*)d_in[3];
    const float* avec = (const float*)d_in[4];
    const float* W1   = (const float*)d_in[5];
    const float* b1   = (const float*)d_in[6];
    const float* W2   = (const float*)d_in[7];
    const float* b2   = (const float*)d_in[8];
    const int*   row  = (const int*)d_in[9];   // edge_index[0]; edge_index[1] is structured
    float* out = (float*)d_out;

    // ws layout: P[N] | Q[N] | V[N] | pool[200*64] | yb[N*32 u32 (bf16x2 y, 128B rows)]
    float* P    = (float*)d_ws;
    float* Q    = P + N_NODES;
    float* V    = Q + N_NODES;
    float* pool = V + N_NODES;
    uint32_t* yb = (uint32_t*)(pool + G_GRAPHS * 64);

    k_touch<<<2048, 256, 0, stream>>>(x, row, P);
    k_node<<<N_NODES / 160, 256, 0, stream>>>(x, Wlin, Watt, avec, P, Q, yb, pool);
    k_edges<<<E_EDGES / 256, 256, 0, stream>>>(row, P, Q, V);
    k_agg<<<N_NODES / 32, 256, 0, stream>>>(row, V, Q, yb, blin, pool);
    k_cls<<<G_GRAPHS, 128, 0, stream>>>(pool, W1, b1, W2, b2, out);
}